// Round 15
// baseline (661.055 us; speedup 1.0000x reference)
//
#include <hip/hip_runtime.h>
#include <cstdint>
#include <cstddef>

namespace {

constexpr int Bb = 8;
constexpr int Nn = 2048;
constexpr int Dd = 1024;
constexpr int NT = 64;  // kv tiles of 32

typedef _Float16 half8 __attribute__((ext_vector_type(8)));
typedef float f32x2v __attribute__((ext_vector_type(2)));
typedef float f32x4v __attribute__((ext_vector_type(4)));
typedef float f32x16v __attribute__((ext_vector_type(16)));
typedef unsigned int v2u __attribute__((ext_vector_type(2)));
typedef unsigned int v4u __attribute__((ext_vector_type(4)));

__device__ __forceinline__ float fast_exp2(float x) {
  float r;
  asm("v_exp_f32 %0, %1\n\ts_nop 1" : "=v"(r) : "v"(x));
  return r;
}

// pack two f32 -> one u32 of 2x fp16 (RTZ); src0 -> low 16 bits
__device__ __forceinline__ unsigned cvt2(float a, float b) {
  return __builtin_bit_cast(unsigned, __builtin_amdgcn_cvt_pkrtz(a, b));
}

// DPP lane exchange (VALU pipe), CTRL compile-time.
template <int CTRL>
__device__ __forceinline__ float dpp_f(float v) {
  return __builtin_bit_cast(
      float, __builtin_amdgcn_update_dpp(0, __builtin_bit_cast(int, v), CTRL,
                                         0xF, 0xF, true));
}
// reduce over a 16-lane row: quad xor1, xor2, then row_ror 4, 8.
__device__ __forceinline__ float red16_max(float v) {
  v = fmaxf(v, dpp_f<0xB1>(v));
  v = fmaxf(v, dpp_f<0x4E>(v));
  v = fmaxf(v, dpp_f<0x124>(v));
  v = fmaxf(v, dpp_f<0x128>(v));
  return v;
}
__device__ __forceinline__ float red16_add(float v) {
  v = v + dpp_f<0xB1>(v);
  v = v + dpp_f<0x4E>(v);
  v = v + dpp_f<0x124>(v);
  v = v + dpp_f<0x128>(v);
  return v;
}

__device__ __forceinline__ void barrier_lgkm() {
  asm volatile("s_waitcnt lgkmcnt(0)" ::: "memory");
  __builtin_amdgcn_s_barrier();
  __builtin_amdgcn_sched_barrier(0);
}
// counted drain: P/scale/flag writes (older than the 16 tr + 8 stage ops)
// are retired once outstanding <= 15; tr/stage may stay in flight.
__device__ __forceinline__ void barrier_lgkm15() {
  asm volatile("s_waitcnt lgkmcnt(15)" ::: "memory");
  __builtin_amdgcn_s_barrier();
  __builtin_amdgcn_sched_barrier(0);
}

// fp32 -> packed fp16 stream (same element order, 2B/elem)
__global__ void convf16(const float* __restrict__ in, v4u* __restrict__ out) {
  const int n8 = Bb * Nn * Dd / 8;
  int i = blockIdx.x * blockDim.x + threadIdx.x;
  const int stride = gridDim.x * blockDim.x;
  const f32x4v* in4 = (const f32x4v*)in;
  for (; i < n8; i += stride) {
    f32x4v a = in4[2 * i], b = in4[2 * i + 1];
    v4u p;
    p[0] = cvt2(a[0], a[1]);
    p[1] = cvt2(a[2], a[3]);
    p[2] = cvt2(b[0], b[1]);
    p[3] = cvt2(b[2], b[3]);
    out[i] = p;
  }
}

template <int WS>
__device__ __forceinline__ v4u ld8h(const float* f32p, const v4u* h16p) {
  if constexpr (WS) {
    return *h16p;
  } else {
    f32x4v a = *(const f32x4v*)f32p;
    f32x4v b = *(const f32x4v*)(f32p + 4);
    v4u p;
    p[0] = cvt2(a[0], a[1]);
    p[1] = cvt2(a[2], a[3]);
    p[2] = cvt2(b[0], b[1]);
    p[3] = cvt2(b[2], b[3]);
    return p;
  }
}

// Flash attention fwd (no scale), K == V == Y. 512 threads = 8 waves:
// wave = (kvf in 0..1) x (ds in 0..3, 256-d slice). QB=32, KVB=32.
// 2-barrier tile, double-buffered ybuf, all-wave softmax:
//  ph A: S(t) from s | LOADY(s,t+1) | pscr2 wr                      [B1 lgkm0]
//  ph B: all waves: softmax own 4 q-rows | P/scale/flag wr |
//        ISSUE_TR(t, buf cur) | STAGE_WR(s -> buf nxt)              [B2 lgkm15]
//  ph C: flag+pa rd | rescale | lgkm(0) | 8 PV MFMA        (no end barrier)
template <int WS>
__global__ __launch_bounds__(512, 2) void flash_fwd(
    const float* __restrict__ Qf, const float* __restrict__ Yf,
    const v4u* __restrict__ Qw, const v4u* __restrict__ Yw,
    float* __restrict__ Om) {
  // per-buffer tr-window layout:
  // addr(kv,d) = (kv>>2)*8192 + (d>>4)*128 + (kv&3)*32 + (d&15)*2
  __shared__ __attribute__((aligned(128))) char ybuf[2][65536];
  __shared__ __attribute__((aligned(16))) float pscr2[4][32][36];
  __shared__ __attribute__((aligned(16))) char Pb[2048];  // [oct][q] 16B
  __shared__ float sscale[32];
  __shared__ float sinvl[32];
  __shared__ int flags[2];

  const int tid = (int)threadIdx.x;
  const int w = tid >> 6, l = tid & 63;
  const int lm = l & 15, g = (l >> 4) & 3, g2 = (l >> 5) & 1, l31 = l & 31;
  const int kvf = w >> 2, ds = w & 3;
  const int bid = (int)blockIdx.x, batch = bid & 7, row0 = (bid >> 3) * 32;
  const size_t bY = (size_t)batch * Nn;

  // ---- Q fragments (B-operand): lane(lm,g): q = qh*16+lm,
  // d = ds*256 + ks*32 + g*8 + i   (ks = 0..7)
  v4u qreg[2][8];
#pragma unroll
  for (int qh = 0; qh < 2; ++qh)
#pragma unroll
    for (int ks = 0; ks < 8; ++ks) {
      const int rr = row0 + qh * 16 + lm;
      const int dd_ = ds * 256 + ks * 32 + g * 8;
      qreg[qh][ks] = ld8h<WS>(Qf + (size_t)(bY + rr) * Dd + dd_,
                              Qw + (size_t)(bY + rr) * 128 + (dd_ >> 3));
    }

#define LOADY(dst, t_)                                                        \
  do {                                                                        \
    const int rr_ = (t_)*32 + kvf * 16 + lm;                                  \
    _Pragma("unroll") for (int ks = 0; ks < 8; ++ks) {                        \
      const int dd_ = ds * 256 + ks * 32 + g * 8;                             \
      dst[ks] = ld8h<WS>(Yf + (size_t)(bY + rr_) * Dd + dd_,                  \
                         Yw + (size_t)(bY + rr_) * 128 + (dd_ >> 3));         \
    }                                                                         \
  } while (0)

  // staging write: lane(lm,g) kv=kvf*16+lm, d=ds*256+ks*32+g*8 (16B half-row)
  const unsigned sbase =
      (unsigned)((kvf * 4 + (lm >> 2)) * 8192 + (ds * 16 + (g >> 1)) * 128 +
                 (lm & 3) * 32 + (g & 1) * 16);
#define STAGE_WR(SRC, BASE)                                                   \
  do {                                                                        \
    _Pragma("unroll") for (int ks = 0; ks < 8; ++ks)                          \
        *(v4u*)((BASE) + sbase + ks * 256) = SRC[ks];                         \
  } while (0)

  char* const yb0 = &ybuf[0][0];
  v4u s[8];
  LOADY(s, 0);
  STAGE_WR(s, yb0);  // tile 0 -> buf 0
  if (tid == 0) {
    flags[0] = 0;
    flags[1] = 0;
  }

  f32x16v Oacc[4];
#pragma unroll
  for (int i = 0; i < 4; ++i)
#pragma unroll
    for (int j = 0; j < 16; ++j) Oacc[i][j] = 0.0f;

  float m_run = -__builtin_inff();
  float l_run = 0.0f;
  const unsigned ylds = (unsigned)(uintptr_t)yb0;
  constexpr float L2E = 1.44269504088896f;

  __syncthreads();

  for (int t = 0; t < NT; ++t) {
    const unsigned ytr = ylds + (unsigned)((t & 1) * 65536);  // PV source
    char* const ybn = yb0 + (((t + 1) & 1) * 65536);          // stage target

    // ---- phase A: S MFMAs + prefetch + partial store
    f32x4v acc0 = {0.f, 0.f, 0.f, 0.f}, acc1 = {0.f, 0.f, 0.f, 0.f};
#pragma unroll
    for (int ks = 0; ks < 8; ++ks) {
      half8 av = __builtin_bit_cast(half8, s[ks]);
      acc0 = __builtin_amdgcn_mfma_f32_16x16x32_f16(
          av, __builtin_bit_cast(half8, qreg[0][ks]), acc0, 0, 0, 0);
      acc1 = __builtin_amdgcn_mfma_f32_16x16x32_f16(
          av, __builtin_bit_cast(half8, qreg[1][ks]), acc1, 0, 0, 0);
    }
    LOADY(s, (t + 1) & 63);
    *(f32x4v*)&pscr2[ds][lm][kvf * 16 + g * 4] = acc0;
    *(f32x4v*)&pscr2[ds][16 + lm][kvf * 16 + g * 4] = acc1;
    barrier_lgkm();  // B1: partials visible

    // ---- phase B: all-wave softmax (4 q-rows per wave) + tr issue + stage
    {
      const int rq = 4 * w + (l >> 4);  // this lane's q row
      const int c = l & 15;             // kv pair index (kv = 2c, 2c+1)
      float s0 = 0.f, s1 = 0.f;
#pragma unroll
      for (int sl = 0; sl < 4; ++sl) {
        f32x2v p_ = *(const f32x2v*)&pscr2[sl][rq][2 * c];
        s0 += p_[0];
        s1 += p_[1];
      }
      float pm = red16_max(fmaxf(s0, s1));
      bool defer = (pm <= m_run + 8.0f);
      bool allw = (bool)__all((int)defer);
      float scale = 1.0f;
      if (!allw) {
        float mn = fmaxf(m_run, pm);
        scale = fast_exp2((m_run - mn) * L2E);
        m_run = mn;
      }
      float e0 = fast_exp2((s0 - m_run) * L2E);
      float e1 = fast_exp2((s1 - m_run) * L2E);
      float ps = red16_add(e0 + e1);
      l_run = l_run * scale + ps;
      // P[q rq][kv 2c..2c+1] in [oct][q] layout
      *(unsigned*)(Pb + (c >> 2) * 512 + rq * 16 + (c & 3) * 4) = cvt2(e0, e1);
      if (c == 0) sscale[rq] = scale;
      if (l == 0 && !allw) flags[t & 1] = 1;  // benign same-value race
    }
    if (tid == 0) flags[(t + 1) & 1] = 0;  // zero next slot (read C(t+1))

    v2u trr[16];
#pragma unroll
    for (int kb = 0; kb < 2; ++kb)
#pragma unroll
      for (int df = 0; df < 4; ++df) {
        const unsigned wb =
            ytr + (unsigned)((kb * 4 + g2 * 2) * 8192 +
                             ((w * 4 + df) * 2 + (l31 >> 4)) * 128 +
                             (l31 & 15) * 8);
        asm volatile("ds_read_b64_tr_b16 %0, %1"
                     : "=v"(trr[kb * 8 + df * 2])
                     : "v"(wb));
        asm volatile("ds_read_b64_tr_b16 %0, %1"
                     : "=v"(trr[kb * 8 + df * 2 + 1])
                     : "v"(wb + 8192u));
      }
    STAGE_WR(s, ybn);  // tile t+1 -> other buffer (overlaps tr/softmax)
    barrier_lgkm15();  // B2: P/scale/flag drained; tr+stage stay in flight

    // ---- phase C: PV
    const int flg = flags[t & 1];
    half8 pa0 = *(const half8*)(Pb + g2 * 512 + l31 * 16);
    half8 pa1 = *(const half8*)(Pb + (2 + g2) * 512 + l31 * 16);
    if (flg) {
#pragma unroll
      for (int df = 0; df < 4; ++df)
#pragma unroll
        for (int r = 0; r < 16; ++r) {
          const int q_ = (r & 3) + 8 * (r >> 2) + 4 * g2;
          Oacc[df][r] *= sscale[q_];
        }
    }
    asm volatile("s_waitcnt lgkmcnt(0)" ::: "memory");
    __builtin_amdgcn_sched_barrier(0);
#pragma unroll
    for (int kb = 0; kb < 2; ++kb)
#pragma unroll
      for (int df = 0; df < 4; ++df) {
        v4u bu;
        bu[0] = trr[kb * 8 + df * 2][0];
        bu[1] = trr[kb * 8 + df * 2][1];
        bu[2] = trr[kb * 8 + df * 2 + 1][0];
        bu[3] = trr[kb * 8 + df * 2 + 1][1];
        Oacc[df] = __builtin_amdgcn_mfma_f32_32x32x16_f16(
            kb ? pa1 : pa0, __builtin_bit_cast(half8, bu), Oacc[df], 0, 0, 0);
      }
    // no end-of-tile barrier: next B1 orders everything (audit in header)
  }

  // ---- epilogue
  if ((l & 15) == 0) sinvl[4 * w + (l >> 4)] = 1.0f / l_run;
  __syncthreads();
#pragma unroll
  for (int df = 0; df < 4; ++df)
#pragma unroll
    for (int r = 0; r < 16; ++r) {
      const int q_ = (r & 3) + 8 * (r >> 2) + 4 * g2;
      const float inv = sinvl[q_];
      Om[(size_t)(bY + row0 + q_) * Dd + (w * 4 + df) * 32 + l31] =
          Oacc[df][r] * inv;
    }
#undef STAGE_WR
#undef LOADY
}

}  // namespace

extern "C" void kernel_launch(void* const* d_in, const int* in_sizes, int n_in,
                              void* d_out, int out_size, void* d_ws,
                              size_t ws_size, hipStream_t stream) {
  (void)in_sizes; (void)n_in; (void)out_size;
  const float* x = (const float*)d_in[0];
  const float* y = (const float*)d_in[1];
  float* A = (float*)d_out;
  float* Bo = A + (size_t)Bb * Nn * Dd;
  const size_t halfws = (size_t)Bb * Nn * Dd * 2;  // 32 MiB per matrix
  dim3 fg(512), fb(512);
  if (d_ws != nullptr && ws_size >= 2 * halfws) {
    v4u* Xw = (v4u*)d_ws;
    v4u* Yw = (v4u*)((char*)d_ws + halfws);
    hipLaunchKernelGGL(convf16, dim3(2048), dim3(256), 0, stream, x, Xw);
    hipLaunchKernelGGL(convf16, dim3(2048), dim3(256), 0, stream, y, Yw);
    hipLaunchKernelGGL(flash_fwd<1>, fg, fb, 0, stream, x, y, Xw, Yw, A);
    hipLaunchKernelGGL(flash_fwd<1>, fg, fb, 0, stream, y, x, Yw, Xw, Bo);
  } else {
    hipLaunchKernelGGL(flash_fwd<0>, fg, fb, 0, stream, x, y, (const v4u*)x,
                       (const v4u*)y, A);
    hipLaunchKernelGGL(flash_fwd<0>, fg, fb, 0, stream, y, x, (const v4u*)y,
                       (const v4u*)x, Bo);
  }
}

// Round 16
// 547.596 us; speedup vs baseline: 1.2072x; 1.2072x over previous
//
#include <hip/hip_runtime.h>
#include <cstdint>
#include <cstddef>

namespace {

constexpr int Bb = 8;
constexpr int Nn = 2048;
constexpr int Dd = 1024;
constexpr int NT = 64;  // kv tiles of 32

typedef _Float16 half8 __attribute__((ext_vector_type(8)));
typedef float f32x2v __attribute__((ext_vector_type(2)));
typedef float f32x4v __attribute__((ext_vector_type(4)));
typedef float f32x16v __attribute__((ext_vector_type(16)));
typedef unsigned int v2u __attribute__((ext_vector_type(2)));
typedef unsigned int v4u __attribute__((ext_vector_type(4)));

__device__ __forceinline__ float fast_exp2(float x) {
  float r;
  asm("v_exp_f32 %0, %1\n\ts_nop 1" : "=v"(r) : "v"(x));
  return r;
}

// pack two f32 -> one u32 of 2x fp16 (RTZ); src0 -> low 16 bits
__device__ __forceinline__ unsigned cvt2(float a, float b) {
  return __builtin_bit_cast(unsigned, __builtin_amdgcn_cvt_pkrtz(a, b));
}

// DPP lane exchange (VALU pipe), CTRL compile-time.
template <int CTRL>
__device__ __forceinline__ float dpp_f(float v) {
  return __builtin_bit_cast(
      float, __builtin_amdgcn_update_dpp(0, __builtin_bit_cast(int, v), CTRL,
                                         0xF, 0xF, true));
}
// reduce over a 16-lane row: quad xor1, xor2, then row_ror 4, 8.
__device__ __forceinline__ float red16_max(float v) {
  v = fmaxf(v, dpp_f<0xB1>(v));
  v = fmaxf(v, dpp_f<0x4E>(v));
  v = fmaxf(v, dpp_f<0x124>(v));
  v = fmaxf(v, dpp_f<0x128>(v));
  return v;
}
__device__ __forceinline__ float red16_add(float v) {
  v = v + dpp_f<0xB1>(v);
  v = v + dpp_f<0x4E>(v);
  v = v + dpp_f<0x124>(v);
  v = v + dpp_f<0x128>(v);
  return v;
}

__device__ __forceinline__ void barrier_lgkm() {
  asm volatile("s_waitcnt lgkmcnt(0)" ::: "memory");
  __builtin_amdgcn_s_barrier();
  __builtin_amdgcn_sched_barrier(0);
}
__device__ __forceinline__ void barrier_plain() {
  __builtin_amdgcn_s_barrier();
  __builtin_amdgcn_sched_barrier(0);
}

// fp32 -> packed fp16 stream (same element order, 2B/elem)
__global__ void convf16(const float* __restrict__ in, v4u* __restrict__ out) {
  const int n8 = Bb * Nn * Dd / 8;
  int i = blockIdx.x * blockDim.x + threadIdx.x;
  const int stride = gridDim.x * blockDim.x;
  const f32x4v* in4 = (const f32x4v*)in;
  for (; i < n8; i += stride) {
    f32x4v a = in4[2 * i], b = in4[2 * i + 1];
    v4u p;
    p[0] = cvt2(a[0], a[1]);
    p[1] = cvt2(a[2], a[3]);
    p[2] = cvt2(b[0], b[1]);
    p[3] = cvt2(b[2], b[3]);
    out[i] = p;
  }
}

template <int WS>
__device__ __forceinline__ v4u ld8h(const float* f32p, const v4u* h16p) {
  if constexpr (WS) {
    return *h16p;
  } else {
    f32x4v a = *(const f32x4v*)f32p;
    f32x4v b = *(const f32x4v*)(f32p + 4);
    v4u p;
    p[0] = cvt2(a[0], a[1]);
    p[1] = cvt2(a[2], a[3]);
    p[2] = cvt2(b[0], b[1]);
    p[3] = cvt2(b[2], b[3]);
    return p;
  }
}

// Flash attention fwd (no scale), K == V == Y. 512 threads = 8 waves:
// wave = (kvf in 0..1) x (ds in 0..3, 256-d slice). QB=32, KVB=32.
// R12-champion schedule (3 barriers, STAGE at tile end) with the softmax
// distributed across all 8 waves (4 q-rows each, DPP 16-lane reductions).
template <int WS>
__global__ __launch_bounds__(512, 2) void flash_fwd(
    const float* __restrict__ Qf, const float* __restrict__ Yf,
    const v4u* __restrict__ Qw, const v4u* __restrict__ Yw,
    float* __restrict__ Om) {
  // ybuf tr-window layout:
  // addr(kv,d) = (kv>>2)*8192 + (d>>4)*128 + (kv&3)*32 + (d&15)*2
  __shared__ __attribute__((aligned(128))) char ybuf[65536];
  // pscr2[ds][q][kv] f32, kv-row padded 32->36
  __shared__ __attribute__((aligned(16))) float pscr2[4][32][36];
  __shared__ __attribute__((aligned(16))) char Pb[2048];  // [oct][q] 16B
  __shared__ float sscale[32];
  __shared__ float sinvl[32];
  __shared__ __attribute__((aligned(16))) int sflag8[8];

  const int tid = (int)threadIdx.x;
  const int w = tid >> 6, l = tid & 63;
  const int lm = l & 15, g = (l >> 4) & 3, g2 = (l >> 5) & 1, l31 = l & 31;
  const int kvf = w >> 2, ds = w & 3;
  const int bid = (int)blockIdx.x, batch = bid & 7, row0 = (bid >> 3) * 32;
  const size_t bY = (size_t)batch * Nn;

  // ---- Q fragments (B-operand): lane(lm,g): q = qh*16+lm,
  // d = ds*256 + ks*32 + g*8 + i   (ks = 0..7)
  v4u qreg[2][8];
#pragma unroll
  for (int qh = 0; qh < 2; ++qh)
#pragma unroll
    for (int ks = 0; ks < 8; ++ks) {
      const int rr = row0 + qh * 16 + lm;
      const int dd_ = ds * 256 + ks * 32 + g * 8;
      qreg[qh][ks] = ld8h<WS>(Qf + (size_t)(bY + rr) * Dd + dd_,
                              Qw + (size_t)(bY + rr) * 128 + (dd_ >> 3));
    }

#define LOADY(dst, t_)                                                        \
  do {                                                                        \
    const int rr_ = (t_)*32 + kvf * 16 + lm;                                  \
    _Pragma("unroll") for (int ks = 0; ks < 8; ++ks) {                        \
      const int dd_ = ds * 256 + ks * 32 + g * 8;                             \
      dst[ks] = ld8h<WS>(Yf + (size_t)(bY + rr_) * Dd + dd_,                  \
                         Yw + (size_t)(bY + rr_) * 128 + (dd_ >> 3));         \
    }                                                                         \
  } while (0)

  // staging write: lane(lm,g) kv=kvf*16+lm, d=ds*256+ks*32+g*8 (16B half-row)
  const unsigned sbase =
      (unsigned)((kvf * 4 + (lm >> 2)) * 8192 + (ds * 16 + (g >> 1)) * 128 +
                 (lm & 3) * 32 + (g & 1) * 16);
#define STAGE_WR(SRC)                                                         \
  do {                                                                        \
    _Pragma("unroll") for (int ks = 0; ks < 8; ++ks)                          \
        *(v4u*)(ybuf + sbase + ks * 256) = SRC[ks];                           \
  } while (0)

  v4u s[8];
  LOADY(s, 0);
  STAGE_WR(s);

  f32x16v Oacc[4];
#pragma unroll
  for (int i = 0; i < 4; ++i)
#pragma unroll
    for (int j = 0; j < 16; ++j) Oacc[i][j] = 0.0f;

  float m_run = -__builtin_inff();
  float l_run = 0.0f;
  const unsigned ylds = (unsigned)(uintptr_t)&ybuf[0];
  constexpr float L2E = 1.44269504088896f;

  v2u trr[16];

#define ISSUE_TR()                                                            \
  do {                                                                        \
    _Pragma("unroll") for (int kb = 0; kb < 2; ++kb)                          \
        _Pragma("unroll") for (int df = 0; df < 4; ++df) {                    \
      const unsigned wb =                                                     \
          ylds + (unsigned)((kb * 4 + g2 * 2) * 8192 +                        \
                            ((w * 4 + df) * 2 + (l31 >> 4)) * 128 +           \
                            (l31 & 15) * 8);                                  \
      asm volatile("ds_read_b64_tr_b16 %0, %1"                                \
                   : "=v"(trr[kb * 8 + df * 2])                               \
                   : "v"(wb));                                                \
      asm volatile("ds_read_b64_tr_b16 %0, %1"                                \
                   : "=v"(trr[kb * 8 + df * 2 + 1])                           \
                   : "v"(wb + 8192u));                                        \
    }                                                                         \
  } while (0)

  __syncthreads();

#define TILE_BODY(t_)                                                         \
  do {                                                                        \
    f32x4v acc0 = {0.f, 0.f, 0.f, 0.f}, acc1 = {0.f, 0.f, 0.f, 0.f};          \
    _Pragma("unroll") for (int ks = 0; ks < 8; ++ks) {                        \
      half8 av = __builtin_bit_cast(half8, s[ks]);                            \
      acc0 = __builtin_amdgcn_mfma_f32_16x16x32_f16(                          \
          av, __builtin_bit_cast(half8, qreg[0][ks]), acc0, 0, 0, 0);         \
      acc1 = __builtin_amdgcn_mfma_f32_16x16x32_f16(                          \
          av, __builtin_bit_cast(half8, qreg[1][ks]), acc1, 0, 0, 0);         \
    }                                                                         \
    LOADY(s, ((t_) + 1) & 63);                                                \
    *(f32x4v*)&pscr2[ds][lm][kvf * 16 + g * 4] = acc0;                        \
    *(f32x4v*)&pscr2[ds][16 + lm][kvf * 16 + g * 4] = acc1;                   \
    barrier_lgkm(); /* B1: partials + ybuf(t) visible */                      \
    { /* all-wave softmax: this wave owns q rows 4w..4w+3 */                  \
      const int rq = 4 * w + (l >> 4); /* q row */                            \
      const int c = l & 15;            /* kv pair (kv = 2c, 2c+1) */          \
      float s0 = 0.f, s1 = 0.f;                                               \
      _Pragma("unroll") for (int sl = 0; sl < 4; ++sl) {                      \
        f32x2v p_ = *(const f32x2v*)&pscr2[sl][rq][2 * c];                    \
        s0 += p_[0];                                                          \
        s1 += p_[1];                                                          \
      }                                                                       \
      float pm = red16_max(fmaxf(s0, s1));                                    \
      bool defer = (pm <= m_run + 8.0f);                                      \
      bool allw = (bool)__all((int)defer);                                    \
      float scale = 1.0f;                                                     \
      if (!allw) {                                                            \
        float mn = fmaxf(m_run, pm);                                          \
        scale = fast_exp2((m_run - mn) * L2E);                                \
        m_run = mn;                                                           \
      }                                                                       \
      float e0 = fast_exp2((s0 - m_run) * L2E);                               \
      float e1 = fast_exp2((s1 - m_run) * L2E);                               \
      float ps = red16_add(e0 + e1);                                          \
      l_run = l_run * scale + ps;                                             \
      *(unsigned*)(Pb + (c >> 2) * 512 + rq * 16 + (c & 3) * 4) =             \
          cvt2(e0, e1);                                                       \
      if (c == 0) sscale[rq] = scale;                                         \
      if (l == 0) sflag8[w] = allw ? 0 : 1;                                   \
    }                                                                         \
    ISSUE_TR();                                                               \
    barrier_lgkm(); /* B2: P + stats visible; tr data in regs */              \
    half8 pa0 = *(const half8*)(Pb + g2 * 512 + l31 * 16);                    \
    half8 pa1 = *(const half8*)(Pb + (2 + g2) * 512 + l31 * 16);              \
    v4u f0 = *(const v4u*)&sflag8[0];                                         \
    v4u f1 = *(const v4u*)&sflag8[4];                                         \
    if (f0[0] | f0[1] | f0[2] | f0[3] | f1[0] | f1[1] | f1[2] | f1[3]) {      \
      _Pragma("unroll") for (int df = 0; df < 4; ++df)                        \
          _Pragma("unroll") for (int r = 0; r < 16; ++r) {                    \
        const int q_ = (r & 3) + 8 * (r >> 2) + 4 * g2;                       \
        Oacc[df][r] *= sscale[q_];                                            \
      }                                                                       \
    }                                                                         \
    asm volatile("s_waitcnt lgkmcnt(0)" ::: "memory");                        \
    __builtin_amdgcn_sched_barrier(0);                                        \
    _Pragma("unroll") for (int kb = 0; kb < 2; ++kb)                          \
        _Pragma("unroll") for (int df = 0; df < 4; ++df) {                    \
      v4u bu;                                                                 \
      bu[0] = trr[kb * 8 + df * 2][0];                                        \
      bu[1] = trr[kb * 8 + df * 2][1];                                        \
      bu[2] = trr[kb * 8 + df * 2 + 1][0];                                    \
      bu[3] = trr[kb * 8 + df * 2 + 1][1];                                    \
      Oacc[df] = __builtin_amdgcn_mfma_f32_32x32x16_f16(                      \
          kb ? pa1 : pa0, __builtin_bit_cast(half8, bu), Oacc[df], 0, 0, 0);  \
    }                                                                         \
    barrier_plain(); /* B3: PV/pscr/Pb reads done, ybuf free */               \
    STAGE_WR(s);                                                              \
  } while (0)

  for (int t = 0; t < NT; ++t) {
    TILE_BODY(t);
  }

  // ---- epilogue
  if ((l & 15) == 0) sinvl[4 * w + (l >> 4)] = 1.0f / l_run;
  __syncthreads();
#pragma unroll
  for (int df = 0; df < 4; ++df)
#pragma unroll
    for (int r = 0; r < 16; ++r) {
      const int q_ = (r & 3) + 8 * (r >> 2) + 4 * g2;
      const float inv = sinvl[q_];
      Om[(size_t)(bY + row0 + q_) * Dd + (w * 4 + df) * 32 + l31] =
          Oacc[df][r] * inv;
    }
#undef TILE_BODY
#undef ISSUE_TR
#undef STAGE_WR
#undef LOADY
}

}  // namespace

extern "C" void kernel_launch(void* const* d_in, const int* in_sizes, int n_in,
                              void* d_out, int out_size, void* d_ws,
                              size_t ws_size, hipStream_t stream) {
  (void)in_sizes; (void)n_in; (void)out_size;
  const float* x = (const float*)d_in[0];
  const float* y = (const float*)d_in[1];
  float* A = (float*)d_out;
  float* Bo = A + (size_t)Bb * Nn * Dd;
  const size_t halfws = (size_t)Bb * Nn * Dd * 2;  // 32 MiB per matrix
  dim3 fg(512), fb(512);
  if (d_ws != nullptr && ws_size >= 2 * halfws) {
    v4u* Xw = (v4u*)d_ws;
    v4u* Yw = (v4u*)((char*)d_ws + halfws);
    hipLaunchKernelGGL(convf16, dim3(2048), dim3(256), 0, stream, x, Xw);
    hipLaunchKernelGGL(convf16, dim3(2048), dim3(256), 0, stream, y, Yw);
    hipLaunchKernelGGL(flash_fwd<1>, fg, fb, 0, stream, x, y, Xw, Yw, A);
    hipLaunchKernelGGL(flash_fwd<1>, fg, fb, 0, stream, y, x, Yw, Xw, Bo);
  } else {
    hipLaunchKernelGGL(flash_fwd<0>, fg, fb, 0, stream, x, y, (const v4u*)x,
                       (const v4u*)y, A);
    hipLaunchKernelGGL(flash_fwd<0>, fg, fb, 0, stream, y, x, (const v4u*)y,
                       (const v4u*)x, Bo);
  }
}